// Round 7
// baseline (661.389 us; speedup 1.0000x reference)
//
#include <hip/hip_runtime.h>
#include <hip/hip_bf16.h>

#define N_NODES 100000
#define N_EDGES 3200000
#define N_GRAPHS 125
#define D 64
#define NB 200          // buckets
#define BW 500          // nodes per bucket (NB*BW == N_NODES)
#define CAP 20480       // max edges per bucket (mean 16000, sigma ~126)
#define EPW 16000       // edges per workgroup in bucket_scatter (NB wgs)

// ---------- CSR build (bucketed, LDS-atomic) ----------

__global__ void init_bcursor(int* __restrict__ bcursor) {
    int t = blockIdx.x * blockDim.x + threadIdx.x;
    if (t < NB) bcursor[t] = t * CAP;
}

// partition edges into NB dst-range buckets; writes (src,dst) pairs densely
__global__ void bucket_scatter(const int* __restrict__ src, const int* __restrict__ dst,
                               int* __restrict__ bcursor, int2* __restrict__ pairs) {
    __shared__ int bins[NB];
    int wg = blockIdx.x, t = threadIdx.x;
    int e0 = wg * EPW, e1 = e0 + EPW;
    if (t < NB) bins[t] = 0;
    __syncthreads();
    for (int i = e0 + t; i < e1; i += 256)
        atomicAdd(&bins[dst[i] / BW], 1);
    __syncthreads();
    if (t < NB) {
        int c = bins[t];
        bins[t] = c ? atomicAdd(&bcursor[t], c) : 0;
    }
    __syncthreads();
    for (int i = e0 + t; i < e1; i += 256) {
        int s = src[i], d = dst[i];
        int pos = atomicAdd(&bins[d / BW], 1);
        pairs[pos] = make_int2(s, d);
    }
}

// per-bucket node histogram -> cnt, dis
__global__ void bucket_hist(const int2* __restrict__ pairs, const int* __restrict__ bcursor,
                            int* __restrict__ cnt, float* __restrict__ dis) {
    __shared__ int h[BW];
    int b = blockIdx.x, t = threadIdx.x;
    for (int i = t; i < BW; i += 256) h[i] = 0;
    __syncthreads();
    int base = b * CAP, n = bcursor[b] - base;
    int nb = b * BW;
    for (int i = t; i < n; i += 256)
        atomicAdd(&h[pairs[base + i].y - nb], 1);
    __syncthreads();
    for (int i = t; i < BW; i += 256) {
        int c = h[i];
        cnt[nb + i] = c;
        dis[nb + i] = rsqrtf((float)c + 1.0f);
    }
}

// per-block sums of cnt
__global__ void scan1_kernel(const int* __restrict__ cnt, int* __restrict__ sums) {
    __shared__ int lds[256];
    int b = blockIdx.x, t = threadIdx.x;
    int base = b * BW;
    int s = 0;
    if (t < BW / 4) {
#pragma unroll
        for (int k = 0; k < 4; ++k) s += cnt[base + t * 4 + k];
    }
    lds[t] = s;
    __syncthreads();
    for (int off = 128; off > 0; off >>= 1) {
        if (t < off) lds[t] += lds[t + off];
        __syncthreads();
    }
    if (t == 0) sums[b] = lds[0];
}

// exclusive scan of NB block sums -> offs; seal row_start[N]
__global__ void scan2_kernel(const int* __restrict__ sums, int* __restrict__ offs,
                             int* __restrict__ row_start) {
    __shared__ int lds[256];
    int t = threadIdx.x;
    int own = (t < NB) ? sums[t] : 0;
    lds[t] = own;
    __syncthreads();
    for (int off = 1; off < 256; off <<= 1) {
        int v = (t >= off) ? lds[t - off] : 0;
        __syncthreads();
        lds[t] += v;
        __syncthreads();
    }
    if (t < NB) offs[t] = lds[t] - own;
    if (t == 0) row_start[N_NODES] = N_EDGES;
}

// within-block exclusive scan -> row_start
__global__ void scan3_kernel(const int* __restrict__ cnt, const int* __restrict__ offs,
                             int* __restrict__ row_start) {
    __shared__ int lds[256];
    int b = blockIdx.x, t = threadIdx.x;
    int base = b * BW;
    int local[4];
    int s = 0;
    if (t < BW / 4) {
#pragma unroll
        for (int k = 0; k < 4; ++k) { local[k] = cnt[base + t * 4 + k]; s += local[k]; }
    }
    lds[t] = s;
    __syncthreads();
    for (int off = 1; off < 256; off <<= 1) {
        int v = (t >= off) ? lds[t - off] : 0;
        __syncthreads();
        lds[t] += v;
        __syncthreads();
    }
    if (t < BW / 4) {
        int pre = lds[t] - s + offs[b];
#pragma unroll
        for (int k = 0; k < 4; ++k) {
            row_start[base + t * 4 + k] = pre;
            pre += local[k];
        }
    }
}

// per-bucket CSR fill with LDS cursors
__global__ void bucket_fill(const int2* __restrict__ pairs, const int* __restrict__ bcursor,
                            const int* __restrict__ row_start, int* __restrict__ csr) {
    __shared__ int cur[BW];
    int b = blockIdx.x, t = threadIdx.x;  // 512 threads
    int nb = b * BW;
    for (int i = t; i < BW; i += 512) cur[i] = row_start[nb + i];
    __syncthreads();
    int base = b * CAP, n = bcursor[b] - base;
    for (int i = t; i < n; i += 512) {
        int2 p = pairs[base + i];
        int pos = atomicAdd(&cur[p.y - nb], 1);
        csr[pos] = p.x;
    }
}

// sort each node's csr segment by src (perf-only: makes co-resident waves'
// reads sweep the same src window -> L2-resident). One wave per node,
// 64-wide shuffle bitonic; deg > 64 left unsorted (prob ~1e-8, still correct).
__global__ void sort_csr_kernel(const int* __restrict__ row_start, int* __restrict__ csr) {
    int v    = (blockIdx.x * blockDim.x + threadIdx.x) >> 6;
    int lane = threadIdx.x & 63;
    if (v >= N_NODES) return;
    int base = row_start[v];
    int n = row_start[v + 1] - base;
    if (n <= 1 || n > 64) return;
    int key = (lane < n) ? csr[base + lane] : 0x7fffffff;
#pragma unroll
    for (int k = 2; k <= 64; k <<= 1) {
        for (int j = k >> 1; j > 0; j >>= 1) {
            int partner = __shfl_xor(key, j);
            bool dir_up   = ((lane & k) == 0);
            bool keep_min = (((lane & j) == 0) == dir_up);
            key = keep_min ? min(key, partner) : max(key, partner);
        }
    }
    if (lane < n) csr[base + lane] = key;
}

// ---------- compute ----------

// Y[r][c] = sum_k X[r][k] * W[k][c] (+ bias[c] if bias != nullptr)
// EXACT R3 version (proven): block = 256 threads -> 4 rows x 64 cols.
__global__ void gemm_kernel(const float* __restrict__ X, const float* __restrict__ W,
                            const float* __restrict__ bias, float* __restrict__ Y,
                            int nrows) {
    __shared__ float Ws[64][64];
    for (int i = threadIdx.x; i < 64 * 64; i += 256)
        Ws[i >> 6][i & 63] = W[i];
    __syncthreads();
    int c  = threadIdx.x & 63;
    int rl = threadIdx.x >> 6;  // 0..3
    int r  = blockIdx.x * 4 + rl;
    if (r < nrows) {
        const float* xr = X + (size_t)r * D;
        float acc = bias ? bias[c] : 0.0f;
#pragma unroll
        for (int k = 0; k < 64; ++k)
            acc = fmaf(xr[k], Ws[k][c], acc);
        Y[(size_t)r * D + c] = acc;
    }
}

// one wave per dst node; half-wave (32 lanes, float2/lane) per edge ->
// 2 edges per iteration, one dwordx2 load instruction covers both rows.
// BYTE-IDENTICAL to R6 (so the sort's effect is cleanly attributable).
__global__ void gather_kernel(const float* __restrict__ H, const int* __restrict__ csr,
                              const int* __restrict__ row_start, const float* __restrict__ dis,
                              const float* __restrict__ bias, float* __restrict__ Bout,
                              int do_relu) {
    int v    = (blockIdx.x * blockDim.x + threadIdx.x) >> 6;
    int lane = threadIdx.x & 63;
    int half = lane >> 5;                 // 0 or 1
    int l32  = lane & 31;
    if (v >= N_NODES) return;
    int base = row_start[v];
    int n = row_start[v + 1] - base;
    float disv = dis[v];
    const float2* H2 = (const float2*)H;

    // acc covers feats {2*l32, 2*l32+1}; half 0 seeds bias + self-loop, half 1 zero
    float2 acc = make_float2(0.0f, 0.0f);
    if (half == 0) {
        float2 hv = H2[(size_t)v * 32 + l32];
        acc.x = fmaf(hv.x, disv * disv, bias[2 * l32]);
        acc.y = fmaf(hv.y, disv * disv, bias[2 * l32 + 1]);
    }

    for (int c = 0; c < n; c += 64) {
        int m = min(64, n - c);
        int sl = 0; float dl = 0.0f;
        if (lane < m) { sl = csr[base + c + lane]; dl = dis[sl]; }
        int mp = (m + 1) >> 1;
#pragma unroll 4
        for (int t = 0; t < mp; ++t) {
            int eidx = 2 * t + half;               // lanes >= m preloaded {0, 0.0} -> contribute 0
            int ssrc  = __shfl(sl, eidx);
            float nrm = __shfl(dl, eidx) * disv;
            float2 hv = H2[(size_t)ssrc * 32 + l32];
            acc.x = fmaf(hv.x, nrm, acc.x);
            acc.y = fmaf(hv.y, nrm, acc.y);
        }
    }
    // cross-half reduce
    acc.x += __shfl_xor(acc.x, 32);
    acc.y += __shfl_xor(acc.y, 32);
    if (half == 0) {
        if (do_relu) { acc.x = fmaxf(acc.x, 0.0f); acc.y = fmaxf(acc.y, 0.0f); }
        ((float2*)Bout)[(size_t)v * 32 + l32] = acc;
    }
}

// one block per graph: mean over contiguous node segment [ptr[g], ptr[g+1])
__global__ void pool_kernel(const float* __restrict__ H, const int* __restrict__ ptr,
                            float* __restrict__ out) {
    int g = blockIdx.x;
    int start = ptr[g], end = ptr[g + 1];
    int lane  = threadIdx.x & 63;
    int chunk = threadIdx.x >> 6;
    float acc = 0.0f;
    for (int r = start + chunk; r < end; r += 4)
        acc += H[(size_t)r * D + lane];
    __shared__ float tmp[4][64];
    tmp[chunk][lane] = acc;
    __syncthreads();
    if (threadIdx.x < 64) {
        float s = tmp[0][lane] + tmp[1][lane] + tmp[2][lane] + tmp[3][lane];
        out[g * D + lane] = s / (float)(end - start);
    }
}

extern "C" void kernel_launch(void* const* d_in, const int* in_sizes, int n_in,
                              void* d_out, int out_size, void* d_ws, size_t ws_size,
                              hipStream_t stream) {
    const float* x   = (const float*)d_in[0];
    const int*   ei  = (const int*)d_in[1];
    const int*   src = ei;
    const int*   dst = ei + N_EDGES;
    const int*   ptr = (const int*)d_in[2];
    const float* W1  = (const float*)d_in[3];
    const float* b1  = (const float*)d_in[4];
    const float* W2  = (const float*)d_in[5];
    const float* b2  = (const float*)d_in[6];
    const float* Wf  = (const float*)d_in[7];
    const float* bfp = (const float*)d_in[8];
    float* out = (float*)d_out;

    // workspace layout (4-byte units)
    int*   cnt       = (int*)d_ws;                  // 100352
    int*   row_start = cnt + 100352;                // 100352 (N+1 used)
    int*   sums      = row_start + 100352;          // 256
    int*   offs      = sums + 256;                  // 256
    int*   bcursor   = offs + 256;                  // 256
    float* P         = (float*)(bcursor + 256);     // 8192 (125*64 used)
    float* dis       = P + 8192;                    // 100352
    int*   csr       = (int*)(dis + 100352);        // 3200000
    float* A         = (float*)(csr + 3200000);     // 6400000
    float* B         = A + (size_t)N_NODES * D;     // 6400000
    int2*  pairs     = (int2*)A;                    // NB*CAP int2, aliases A+B

    // --- CSR build ---
    init_bcursor<<<1, 256, 0, stream>>>(bcursor);
    bucket_scatter<<<NB, 256, 0, stream>>>(src, dst, bcursor, pairs);
    bucket_hist<<<NB, 256, 0, stream>>>(pairs, bcursor, cnt, dis);
    scan1_kernel<<<NB, 256, 0, stream>>>(cnt, sums);
    scan2_kernel<<<1, 256, 0, stream>>>(sums, offs, row_start);
    scan3_kernel<<<NB, 256, 0, stream>>>(cnt, offs, row_start);
    bucket_fill<<<NB, 512, 0, stream>>>(pairs, bcursor, row_start, csr);

    const int grid4 = (N_NODES + 3) / 4;   // 4 rows (or waves) per 256-thread block

    // sort each node's edge list by src (perf-only; enables L2-window sweep)
    sort_csr_kernel<<<grid4, 256, 0, stream>>>(row_start, csr);

    // layer 1: A = x @ W1 ; B = relu(gather(A) + A*dis^2 + b1)
    gemm_kernel<<<grid4, 256, 0, stream>>>(x, W1, nullptr, A, N_NODES);
    gather_kernel<<<grid4, 256, 0, stream>>>(A, csr, row_start, dis, b1, B, 1);

    // layer 2
    gemm_kernel<<<grid4, 256, 0, stream>>>(B, W2, nullptr, A, N_NODES);
    gather_kernel<<<grid4, 256, 0, stream>>>(A, csr, row_start, dis, b2, B, 1);

    // head: pool first (mean commutes with linear head), then tiny GEMM
    pool_kernel<<<N_GRAPHS, 256, 0, stream>>>(B, ptr, P);
    gemm_kernel<<<(N_GRAPHS + 3) / 4, 256, 0, stream>>>(P, Wf, bfp, out, N_GRAPHS);
}

// Round 8
// 586.908 us; speedup vs baseline: 1.1269x; 1.1269x over previous
//
#include <hip/hip_runtime.h>
#include <hip/hip_bf16.h>

#define N_NODES 100000
#define N_EDGES 3200000
#define N_GRAPHS 125
#define D 64
#define NB 200          // buckets
#define BW 500          // nodes per bucket (NB*BW == N_NODES)
#define CAP 20480       // max edges per bucket (mean 16000, sigma ~126)
#define EPW 16000       // edges per workgroup in bucket_scatter (NB wgs)

// ---------- CSR build (bucketed, LDS-atomic) ----------

__global__ void init_bcursor(int* __restrict__ bcursor) {
    int t = blockIdx.x * blockDim.x + threadIdx.x;
    if (t < NB) bcursor[t] = t * CAP;
}

// partition edges into NB dst-range buckets; writes (src,dst) pairs densely
__global__ void bucket_scatter(const int* __restrict__ src, const int* __restrict__ dst,
                               int* __restrict__ bcursor, int2* __restrict__ pairs) {
    __shared__ int bins[NB];
    int wg = blockIdx.x, t = threadIdx.x;
    int e0 = wg * EPW, e1 = e0 + EPW;
    if (t < NB) bins[t] = 0;
    __syncthreads();
    for (int i = e0 + t; i < e1; i += 256)
        atomicAdd(&bins[dst[i] / BW], 1);
    __syncthreads();
    if (t < NB) {
        int c = bins[t];
        bins[t] = c ? atomicAdd(&bcursor[t], c) : 0;
    }
    __syncthreads();
    for (int i = e0 + t; i < e1; i += 256) {
        int s = src[i], d = dst[i];
        int pos = atomicAdd(&bins[d / BW], 1);
        pairs[pos] = make_int2(s, d);
    }
}

// per-bucket node histogram -> cnt, dis
__global__ void bucket_hist(const int2* __restrict__ pairs, const int* __restrict__ bcursor,
                            int* __restrict__ cnt, float* __restrict__ dis) {
    __shared__ int h[BW];
    int b = blockIdx.x, t = threadIdx.x;
    for (int i = t; i < BW; i += 256) h[i] = 0;
    __syncthreads();
    int base = b * CAP, n = bcursor[b] - base;
    int nb = b * BW;
    for (int i = t; i < n; i += 256)
        atomicAdd(&h[pairs[base + i].y - nb], 1);
    __syncthreads();
    for (int i = t; i < BW; i += 256) {
        int c = h[i];
        cnt[nb + i] = c;
        dis[nb + i] = rsqrtf((float)c + 1.0f);
    }
}

// per-block sums of cnt
__global__ void scan1_kernel(const int* __restrict__ cnt, int* __restrict__ sums) {
    __shared__ int lds[256];
    int b = blockIdx.x, t = threadIdx.x;
    int base = b * BW;
    int s = 0;
    if (t < BW / 4) {
#pragma unroll
        for (int k = 0; k < 4; ++k) s += cnt[base + t * 4 + k];
    }
    lds[t] = s;
    __syncthreads();
    for (int off = 128; off > 0; off >>= 1) {
        if (t < off) lds[t] += lds[t + off];
        __syncthreads();
    }
    if (t == 0) sums[b] = lds[0];
}

// exclusive scan of NB block sums -> offs; seal row_start[N]
__global__ void scan2_kernel(const int* __restrict__ sums, int* __restrict__ offs,
                             int* __restrict__ row_start) {
    __shared__ int lds[256];
    int t = threadIdx.x;
    int own = (t < NB) ? sums[t] : 0;
    lds[t] = own;
    __syncthreads();
    for (int off = 1; off < 256; off <<= 1) {
        int v = (t >= off) ? lds[t - off] : 0;
        __syncthreads();
        lds[t] += v;
        __syncthreads();
    }
    if (t < NB) offs[t] = lds[t] - own;
    if (t == 0) row_start[N_NODES] = N_EDGES;
}

// within-block exclusive scan -> row_start
__global__ void scan3_kernel(const int* __restrict__ cnt, const int* __restrict__ offs,
                             int* __restrict__ row_start) {
    __shared__ int lds[256];
    int b = blockIdx.x, t = threadIdx.x;
    int base = b * BW;
    int local[4];
    int s = 0;
    if (t < BW / 4) {
#pragma unroll
        for (int k = 0; k < 4; ++k) { local[k] = cnt[base + t * 4 + k]; s += local[k]; }
    }
    lds[t] = s;
    __syncthreads();
    for (int off = 1; off < 256; off <<= 1) {
        int v = (t >= off) ? lds[t - off] : 0;
        __syncthreads();
        lds[t] += v;
        __syncthreads();
    }
    if (t < BW / 4) {
        int pre = lds[t] - s + offs[b];
#pragma unroll
        for (int k = 0; k < 4; ++k) {
            row_start[base + t * 4 + k] = pre;
            pre += local[k];
        }
    }
}

// per-bucket CSR fill with LDS cursors
__global__ void bucket_fill(const int2* __restrict__ pairs, const int* __restrict__ bcursor,
                            const int* __restrict__ row_start, int* __restrict__ csr) {
    __shared__ int cur[BW];
    int b = blockIdx.x, t = threadIdx.x;  // 512 threads
    int nb = b * BW;
    for (int i = t; i < BW; i += 512) cur[i] = row_start[nb + i];
    __syncthreads();
    int base = b * CAP, n = bcursor[b] - base;
    for (int i = t; i < n; i += 512) {
        int2 p = pairs[base + i];
        int pos = atomicAdd(&cur[p.y - nb], 1);
        csr[pos] = p.x;
    }
}

// ---------- compute ----------

// Y[r][c] = sum_k X[r][k] * W[k][c] (+ bias[c] if bias != nullptr)
// EXACT R3 version (proven): block = 256 threads -> 4 rows x 64 cols.
__global__ void gemm_kernel(const float* __restrict__ X, const float* __restrict__ W,
                            const float* __restrict__ bias, float* __restrict__ Y,
                            int nrows) {
    __shared__ float Ws[64][64];
    for (int i = threadIdx.x; i < 64 * 64; i += 256)
        Ws[i >> 6][i & 63] = W[i];
    __syncthreads();
    int c  = threadIdx.x & 63;
    int rl = threadIdx.x >> 6;  // 0..3
    int r  = blockIdx.x * 4 + rl;
    if (r < nrows) {
        const float* xr = X + (size_t)r * D;
        float acc = bias ? bias[c] : 0.0f;
#pragma unroll
        for (int k = 0; k < 64; ++k)
            acc = fmaf(xr[k], Ws[k][c], acc);
        Y[(size_t)r * D + c] = acc;
    }
}

// one wave per dst node; quarter-wave (16 lanes, float4/lane) per edge ->
// 4 edges per iteration, one dwordx4 load instruction covers all four rows.
__global__ void gather_kernel(const float* __restrict__ H, const int* __restrict__ csr,
                              const int* __restrict__ row_start, const float* __restrict__ dis,
                              const float* __restrict__ bias, float* __restrict__ Bout,
                              int do_relu) {
    int v    = (blockIdx.x * blockDim.x + threadIdx.x) >> 6;
    int lane = threadIdx.x & 63;
    int quad = lane >> 4;                 // 0..3
    int l16  = lane & 15;
    if (v >= N_NODES) return;
    int base = row_start[v];
    int n = row_start[v + 1] - base;
    float disv = dis[v];
    const float4* H4 = (const float4*)H;

    // acc covers feats {4*l16 .. 4*l16+3}; quad 0 seeds bias + self-loop
    float4 acc = make_float4(0.0f, 0.0f, 0.0f, 0.0f);
    if (quad == 0) {
        float4 hv = H4[(size_t)v * 16 + l16];
        float ss = disv * disv;
        acc.x = fmaf(hv.x, ss, bias[4 * l16 + 0]);
        acc.y = fmaf(hv.y, ss, bias[4 * l16 + 1]);
        acc.z = fmaf(hv.z, ss, bias[4 * l16 + 2]);
        acc.w = fmaf(hv.w, ss, bias[4 * l16 + 3]);
    }

    for (int c = 0; c < n; c += 64) {
        int m = min(64, n - c);
        int sl = 0; float dl = 0.0f;
        if (lane < m) { sl = csr[base + c + lane]; dl = dis[sl]; }
        int mp = (m + 3) >> 2;
#pragma unroll 4
        for (int t = 0; t < mp; ++t) {
            int eidx = 4 * t + quad;               // lanes >= m preloaded {0, 0.0} -> contribute 0
            int ssrc  = __shfl(sl, eidx);
            float nrm = __shfl(dl, eidx) * disv;
            float4 hv = H4[(size_t)ssrc * 16 + l16];
            acc.x = fmaf(hv.x, nrm, acc.x);
            acc.y = fmaf(hv.y, nrm, acc.y);
            acc.z = fmaf(hv.z, nrm, acc.z);
            acc.w = fmaf(hv.w, nrm, acc.w);
        }
    }
    // reduce across the 4 quads
    acc.x += __shfl_xor(acc.x, 16); acc.y += __shfl_xor(acc.y, 16);
    acc.z += __shfl_xor(acc.z, 16); acc.w += __shfl_xor(acc.w, 16);
    acc.x += __shfl_xor(acc.x, 32); acc.y += __shfl_xor(acc.y, 32);
    acc.z += __shfl_xor(acc.z, 32); acc.w += __shfl_xor(acc.w, 32);
    if (quad == 0) {
        if (do_relu) {
            acc.x = fmaxf(acc.x, 0.0f); acc.y = fmaxf(acc.y, 0.0f);
            acc.z = fmaxf(acc.z, 0.0f); acc.w = fmaxf(acc.w, 0.0f);
        }
        ((float4*)Bout)[(size_t)v * 16 + l16] = acc;
    }
}

// one block per graph: mean over contiguous node segment [ptr[g], ptr[g+1])
__global__ void pool_kernel(const float* __restrict__ H, const int* __restrict__ ptr,
                            float* __restrict__ out) {
    int g = blockIdx.x;
    int start = ptr[g], end = ptr[g + 1];
    int lane  = threadIdx.x & 63;
    int chunk = threadIdx.x >> 6;
    float acc = 0.0f;
    for (int r = start + chunk; r < end; r += 4)
        acc += H[(size_t)r * D + lane];
    __shared__ float tmp[4][64];
    tmp[chunk][lane] = acc;
    __syncthreads();
    if (threadIdx.x < 64) {
        float s = tmp[0][lane] + tmp[1][lane] + tmp[2][lane] + tmp[3][lane];
        out[g * D + lane] = s / (float)(end - start);
    }
}

extern "C" void kernel_launch(void* const* d_in, const int* in_sizes, int n_in,
                              void* d_out, int out_size, void* d_ws, size_t ws_size,
                              hipStream_t stream) {
    const float* x   = (const float*)d_in[0];
    const int*   ei  = (const int*)d_in[1];
    const int*   src = ei;
    const int*   dst = ei + N_EDGES;
    const int*   ptr = (const int*)d_in[2];
    const float* W1  = (const float*)d_in[3];
    const float* b1  = (const float*)d_in[4];
    const float* W2  = (const float*)d_in[5];
    const float* b2  = (const float*)d_in[6];
    const float* Wf  = (const float*)d_in[7];
    const float* bfp = (const float*)d_in[8];
    float* out = (float*)d_out;

    // workspace layout (4-byte units)
    int*   cnt       = (int*)d_ws;                  // 100352
    int*   row_start = cnt + 100352;                // 100352 (N+1 used)
    int*   sums      = row_start + 100352;          // 256
    int*   offs      = sums + 256;                  // 256
    int*   bcursor   = offs + 256;                  // 256
    float* P         = (float*)(bcursor + 256);     // 8192 (125*64 used)
    float* dis       = P + 8192;                    // 100352
    int*   csr       = (int*)(dis + 100352);        // 3200000
    float* A         = (float*)(csr + 3200000);     // 6400000
    float* B         = A + (size_t)N_NODES * D;     // 6400000
    int2*  pairs     = (int2*)A;                    // NB*CAP int2, aliases A+B

    // --- CSR build ---
    init_bcursor<<<1, 256, 0, stream>>>(bcursor);
    bucket_scatter<<<NB, 256, 0, stream>>>(src, dst, bcursor, pairs);
    bucket_hist<<<NB, 256, 0, stream>>>(pairs, bcursor, cnt, dis);
    scan1_kernel<<<NB, 256, 0, stream>>>(cnt, sums);
    scan2_kernel<<<1, 256, 0, stream>>>(sums, offs, row_start);
    scan3_kernel<<<NB, 256, 0, stream>>>(cnt, offs, row_start);
    bucket_fill<<<NB, 512, 0, stream>>>(pairs, bcursor, row_start, csr);

    const int grid4 = (N_NODES + 3) / 4;   // 4 rows (or waves) per 256-thread block

    // layer 1: A = x @ W1 ; B = relu(gather(A) + A*dis^2 + b1)
    gemm_kernel<<<grid4, 256, 0, stream>>>(x, W1, nullptr, A, N_NODES);
    gather_kernel<<<grid4, 256, 0, stream>>>(A, csr, row_start, dis, b1, B, 1);

    // layer 2
    gemm_kernel<<<grid4, 256, 0, stream>>>(B, W2, nullptr, A, N_NODES);
    gather_kernel<<<grid4, 256, 0, stream>>>(A, csr, row_start, dis, b2, B, 1);

    // head: pool first (mean commutes with linear head), then tiny GEMM
    pool_kernel<<<N_GRAPHS, 256, 0, stream>>>(B, ptr, P);
    gemm_kernel<<<(N_GRAPHS + 3) / 4, 256, 0, stream>>>(P, Wf, bfp, out, N_GRAPHS);
}

// Round 9
// 492.182 us; speedup vs baseline: 1.3438x; 1.1925x over previous
//
#include <hip/hip_runtime.h>
#include <hip/hip_bf16.h>

#define N_NODES 100000
#define N_EDGES 3200000
#define N_GRAPHS 125
#define D 64
#define NB 200          // buckets
#define BW 500          // nodes per bucket (NB*BW == N_NODES)
#define CAP 20480       // max edges per bucket (mean 16000, sigma ~126)
#define EPW 16000       // edges per workgroup in bucket_scatter (NB wgs)

__device__ __forceinline__ float bf_lo(unsigned u) { return __uint_as_float(u << 16); }
__device__ __forceinline__ float bf_hi(unsigned u) { return __uint_as_float(u & 0xffff0000u); }

// ---------- CSR build (bucketed, LDS-atomic) ----------

__global__ void init_bcursor(int* __restrict__ bcursor) {
    int t = blockIdx.x * blockDim.x + threadIdx.x;
    if (t < NB) bcursor[t] = t * CAP;
}

// partition edges into NB dst-range buckets; writes (src,dst) pairs densely
__global__ void bucket_scatter(const int* __restrict__ src, const int* __restrict__ dst,
                               int* __restrict__ bcursor, int2* __restrict__ pairs) {
    __shared__ int bins[NB];
    int wg = blockIdx.x, t = threadIdx.x;
    int e0 = wg * EPW, e1 = e0 + EPW;
    if (t < NB) bins[t] = 0;
    __syncthreads();
    for (int i = e0 + t; i < e1; i += 256)
        atomicAdd(&bins[dst[i] / BW], 1);
    __syncthreads();
    if (t < NB) {
        int c = bins[t];
        bins[t] = c ? atomicAdd(&bcursor[t], c) : 0;
    }
    __syncthreads();
    for (int i = e0 + t; i < e1; i += 256) {
        int s = src[i], d = dst[i];
        int pos = atomicAdd(&bins[d / BW], 1);
        pairs[pos] = make_int2(s, d);
    }
}

// per-bucket node histogram -> cnt, dis
__global__ void bucket_hist(const int2* __restrict__ pairs, const int* __restrict__ bcursor,
                            int* __restrict__ cnt, float* __restrict__ dis) {
    __shared__ int h[BW];
    int b = blockIdx.x, t = threadIdx.x;
    for (int i = t; i < BW; i += 256) h[i] = 0;
    __syncthreads();
    int base = b * CAP, n = bcursor[b] - base;
    int nb = b * BW;
    for (int i = t; i < n; i += 256)
        atomicAdd(&h[pairs[base + i].y - nb], 1);
    __syncthreads();
    for (int i = t; i < BW; i += 256) {
        int c = h[i];
        cnt[nb + i] = c;
        dis[nb + i] = rsqrtf((float)c + 1.0f);
    }
}

// per-block sums of cnt
__global__ void scan1_kernel(const int* __restrict__ cnt, int* __restrict__ sums) {
    __shared__ int lds[256];
    int b = blockIdx.x, t = threadIdx.x;
    int base = b * BW;
    int s = 0;
    if (t < BW / 4) {
#pragma unroll
        for (int k = 0; k < 4; ++k) s += cnt[base + t * 4 + k];
    }
    lds[t] = s;
    __syncthreads();
    for (int off = 128; off > 0; off >>= 1) {
        if (t < off) lds[t] += lds[t + off];
        __syncthreads();
    }
    if (t == 0) sums[b] = lds[0];
}

// exclusive scan of NB block sums -> offs; seal row_start[N]
__global__ void scan2_kernel(const int* __restrict__ sums, int* __restrict__ offs,
                             int* __restrict__ row_start) {
    __shared__ int lds[256];
    int t = threadIdx.x;
    int own = (t < NB) ? sums[t] : 0;
    lds[t] = own;
    __syncthreads();
    for (int off = 1; off < 256; off <<= 1) {
        int v = (t >= off) ? lds[t - off] : 0;
        __syncthreads();
        lds[t] += v;
        __syncthreads();
    }
    if (t < NB) offs[t] = lds[t] - own;
    if (t == 0) row_start[N_NODES] = N_EDGES;
}

// within-block exclusive scan -> row_start
__global__ void scan3_kernel(const int* __restrict__ cnt, const int* __restrict__ offs,
                             int* __restrict__ row_start) {
    __shared__ int lds[256];
    int b = blockIdx.x, t = threadIdx.x;
    int base = b * BW;
    int local[4];
    int s = 0;
    if (t < BW / 4) {
#pragma unroll
        for (int k = 0; k < 4; ++k) { local[k] = cnt[base + t * 4 + k]; s += local[k]; }
    }
    lds[t] = s;
    __syncthreads();
    for (int off = 1; off < 256; off <<= 1) {
        int v = (t >= off) ? lds[t - off] : 0;
        __syncthreads();
        lds[t] += v;
        __syncthreads();
    }
    if (t < BW / 4) {
        int pre = lds[t] - s + offs[b];
#pragma unroll
        for (int k = 0; k < 4; ++k) {
            row_start[base + t * 4 + k] = pre;
            pre += local[k];
        }
    }
}

// per-bucket CSR fill with LDS cursors
__global__ void bucket_fill(const int2* __restrict__ pairs, const int* __restrict__ bcursor,
                            const int* __restrict__ row_start, int* __restrict__ csr) {
    __shared__ int cur[BW];
    int b = blockIdx.x, t = threadIdx.x;  // 512 threads
    int nb = b * BW;
    for (int i = t; i < BW; i += 512) cur[i] = row_start[nb + i];
    __syncthreads();
    int base = b * CAP, n = bcursor[b] - base;
    for (int i = t; i < n; i += 512) {
        int2 p = pairs[base + i];
        int pos = atomicAdd(&cur[p.y - nb], 1);
        csr[pos] = p.x;
    }
}

// ---------- compute ----------

// Y[r][c] = sum_k X[r][k] * W[k][c] (+ bias). out_bf16 ? Y is __hip_bfloat16* : float*.
// R3 structure (proven): block = 256 threads -> 4 rows x 64 cols.
__global__ void gemm_kernel(const float* __restrict__ X, const float* __restrict__ W,
                            const float* __restrict__ bias, void* __restrict__ Y,
                            int nrows, int out_bf16) {
    __shared__ float Ws[64][64];
    for (int i = threadIdx.x; i < 64 * 64; i += 256)
        Ws[i >> 6][i & 63] = W[i];
    __syncthreads();
    int c  = threadIdx.x & 63;
    int rl = threadIdx.x >> 6;  // 0..3
    int r  = blockIdx.x * 4 + rl;
    if (r < nrows) {
        const float* xr = X + (size_t)r * D;
        float acc = bias ? bias[c] : 0.0f;
#pragma unroll
        for (int k = 0; k < 64; ++k)
            acc = fmaf(xr[k], Ws[k][c], acc);
        if (out_bf16)
            ((__hip_bfloat16*)Y)[(size_t)r * D + c] = __float2bfloat16(acc);
        else
            ((float*)Y)[(size_t)r * D + c] = acc;
    }
}

// one wave per dst node; 8 lanes per edge, each lane loads uint4 = 8 bf16 feats
// -> 8 edges per wave-iteration, 128 B per row (halved traffic vs fp32).
__global__ void gather_kernel(const __hip_bfloat16* __restrict__ Hb, const int* __restrict__ csr,
                              const int* __restrict__ row_start, const float* __restrict__ dis,
                              const float* __restrict__ bias, float* __restrict__ Bout,
                              int do_relu) {
    int v    = (blockIdx.x * blockDim.x + threadIdx.x) >> 6;
    int lane = threadIdx.x & 63;
    int oct  = lane >> 3;                 // 0..7: edge slot within iteration
    int l8   = lane & 7;                  // feature octet: feats 8*l8 .. 8*l8+7
    if (v >= N_NODES) return;
    int base = row_start[v];
    int n = row_start[v + 1] - base;
    float disv = dis[v];
    const uint4* H4 = (const uint4*)Hb;   // row = 8 x uint4 (64 bf16)

    float a0 = 0, a1 = 0, a2 = 0, a3 = 0, a4 = 0, a5 = 0, a6 = 0, a7 = 0;
    if (oct == 0) {
        uint4 hv = H4[(size_t)v * 8 + l8];
        float ss = disv * disv;
        float4 blo = ((const float4*)bias)[2 * l8];
        float4 bhi = ((const float4*)bias)[2 * l8 + 1];
        a0 = fmaf(bf_lo(hv.x), ss, blo.x); a1 = fmaf(bf_hi(hv.x), ss, blo.y);
        a2 = fmaf(bf_lo(hv.y), ss, blo.z); a3 = fmaf(bf_hi(hv.y), ss, blo.w);
        a4 = fmaf(bf_lo(hv.z), ss, bhi.x); a5 = fmaf(bf_hi(hv.z), ss, bhi.y);
        a6 = fmaf(bf_lo(hv.w), ss, bhi.z); a7 = fmaf(bf_hi(hv.w), ss, bhi.w);
    }

    for (int c = 0; c < n; c += 64) {
        int m = min(64, n - c);
        int sl = 0; float dl = 0.0f;
        if (lane < m) { sl = csr[base + c + lane]; dl = dis[sl]; }
        int mp = (m + 7) >> 3;
#pragma unroll 4
        for (int t = 0; t < mp; ++t) {
            int eidx = 8 * t + oct;                // lanes >= m preloaded {0, 0.0} -> contribute 0
            int ssrc  = __shfl(sl, eidx);
            float nrm = __shfl(dl, eidx) * disv;
            uint4 hv = H4[(size_t)ssrc * 8 + l8];
            a0 = fmaf(bf_lo(hv.x), nrm, a0); a1 = fmaf(bf_hi(hv.x), nrm, a1);
            a2 = fmaf(bf_lo(hv.y), nrm, a2); a3 = fmaf(bf_hi(hv.y), nrm, a3);
            a4 = fmaf(bf_lo(hv.z), nrm, a4); a5 = fmaf(bf_hi(hv.z), nrm, a5);
            a6 = fmaf(bf_lo(hv.w), nrm, a6); a7 = fmaf(bf_hi(hv.w), nrm, a7);
        }
    }
    // reduce across the 8 octs
#pragma unroll
    for (int off = 8; off <= 32; off <<= 1) {
        a0 += __shfl_xor(a0, off); a1 += __shfl_xor(a1, off);
        a2 += __shfl_xor(a2, off); a3 += __shfl_xor(a3, off);
        a4 += __shfl_xor(a4, off); a5 += __shfl_xor(a5, off);
        a6 += __shfl_xor(a6, off); a7 += __shfl_xor(a7, off);
    }
    if (oct == 0) {
        if (do_relu) {
            a0 = fmaxf(a0, 0.0f); a1 = fmaxf(a1, 0.0f); a2 = fmaxf(a2, 0.0f); a3 = fmaxf(a3, 0.0f);
            a4 = fmaxf(a4, 0.0f); a5 = fmaxf(a5, 0.0f); a6 = fmaxf(a6, 0.0f); a7 = fmaxf(a7, 0.0f);
        }
        float4* o = (float4*)Bout + (size_t)v * 16 + 2 * l8;
        o[0] = make_float4(a0, a1, a2, a3);
        o[1] = make_float4(a4, a5, a6, a7);
    }
}

// one block per graph: mean over contiguous node segment [ptr[g], ptr[g+1])
__global__ void pool_kernel(const float* __restrict__ H, const int* __restrict__ ptr,
                            float* __restrict__ out) {
    int g = blockIdx.x;
    int start = ptr[g], end = ptr[g + 1];
    int lane  = threadIdx.x & 63;
    int chunk = threadIdx.x >> 6;
    float acc = 0.0f;
    for (int r = start + chunk; r < end; r += 4)
        acc += H[(size_t)r * D + lane];
    __shared__ float tmp[4][64];
    tmp[chunk][lane] = acc;
    __syncthreads();
    if (threadIdx.x < 64) {
        float s = tmp[0][lane] + tmp[1][lane] + tmp[2][lane] + tmp[3][lane];
        out[g * D + lane] = s / (float)(end - start);
    }
}

extern "C" void kernel_launch(void* const* d_in, const int* in_sizes, int n_in,
                              void* d_out, int out_size, void* d_ws, size_t ws_size,
                              hipStream_t stream) {
    const float* x   = (const float*)d_in[0];
    const int*   ei  = (const int*)d_in[1];
    const int*   src = ei;
    const int*   dst = ei + N_EDGES;
    const int*   ptr = (const int*)d_in[2];
    const float* W1  = (const float*)d_in[3];
    const float* b1  = (const float*)d_in[4];
    const float* W2  = (const float*)d_in[5];
    const float* b2  = (const float*)d_in[6];
    const float* Wf  = (const float*)d_in[7];
    const float* bfp = (const float*)d_in[8];
    float* out = (float*)d_out;

    // workspace layout (4-byte units)
    int*   cnt       = (int*)d_ws;                  // 100352
    int*   row_start = cnt + 100352;                // 100352 (N+1 used)
    int*   sums      = row_start + 100352;          // 256
    int*   offs      = sums + 256;                  // 256
    int*   bcursor   = offs + 256;                  // 256
    float* P         = (float*)(bcursor + 256);     // 8192 (125*64 used)
    float* dis       = P + 8192;                    // 100352
    int*   csr       = (int*)(dis + 100352);        // 3200000
    float* A         = (float*)(csr + 3200000);     // 6400000 (bf16 H uses first half)
    float* B         = A + (size_t)N_NODES * D;     // 6400000
    int2*  pairs     = (int2*)A;                    // NB*CAP int2, aliases A+B (dead before gemm1)
    __hip_bfloat16* Ab = (__hip_bfloat16*)A;        // bf16 H rows, 128 B each

    // --- CSR build ---
    init_bcursor<<<1, 256, 0, stream>>>(bcursor);
    bucket_scatter<<<NB, 256, 0, stream>>>(src, dst, bcursor, pairs);
    bucket_hist<<<NB, 256, 0, stream>>>(pairs, bcursor, cnt, dis);
    scan1_kernel<<<NB, 256, 0, stream>>>(cnt, sums);
    scan2_kernel<<<1, 256, 0, stream>>>(sums, offs, row_start);
    scan3_kernel<<<NB, 256, 0, stream>>>(cnt, offs, row_start);
    bucket_fill<<<NB, 512, 0, stream>>>(pairs, bcursor, row_start, csr);

    const int grid4 = (N_NODES + 3) / 4;   // 4 rows (or waves) per 256-thread block

    // layer 1: Ab = bf16(x @ W1) ; B = relu(gather(Ab) + Ab[v]*dis^2 + b1)
    gemm_kernel<<<grid4, 256, 0, stream>>>(x, W1, nullptr, Ab, N_NODES, 1);
    gather_kernel<<<grid4, 256, 0, stream>>>(Ab, csr, row_start, dis, b1, B, 1);

    // layer 2
    gemm_kernel<<<grid4, 256, 0, stream>>>(B, W2, nullptr, Ab, N_NODES, 1);
    gather_kernel<<<grid4, 256, 0, stream>>>(Ab, csr, row_start, dis, b2, B, 1);

    // head: pool first (mean commutes with linear head), then tiny GEMM (fp32 out)
    pool_kernel<<<N_GRAPHS, 256, 0, stream>>>(B, ptr, P);
    gemm_kernel<<<(N_GRAPHS + 3) / 4, 256, 0, stream>>>(P, Wf, bfp, out, N_GRAPHS, 0);
}

// Round 10
// 394.462 us; speedup vs baseline: 1.6767x; 1.2477x over previous
//
#include <hip/hip_runtime.h>
#include <hip/hip_bf16.h>

#define N_NODES 100000
#define N_EDGES 3200000
#define N_GRAPHS 125
#define D 64
#define NB 200          // buckets
#define BW 500          // nodes per bucket (NB*BW == N_NODES)
#define CAP 20480       // max edges per bucket (mean 16000, sigma ~126)
#define EPW 16000       // edges per workgroup in bucket_scatter (NB wgs)

typedef __bf16 bf16x8 __attribute__((ext_vector_type(8)));
typedef float f32x4 __attribute__((ext_vector_type(4)));

__device__ __forceinline__ float bf_lo(unsigned u) { return __uint_as_float(u << 16); }
__device__ __forceinline__ float bf_hi(unsigned u) { return __uint_as_float(u & 0xffff0000u); }
// RNE float->bf16 bits (matches __float2bfloat16 for normal inputs)
__device__ __forceinline__ unsigned short f2bf(float f) {
    unsigned u = __float_as_uint(f);
    return (unsigned short)((u + 0x7fffu + ((u >> 16) & 1u)) >> 16);
}

// ---------- CSR build (bucketed, LDS-atomic) ----------

__global__ void init_bcursor(int* __restrict__ bcursor) {
    int t = blockIdx.x * blockDim.x + threadIdx.x;
    if (t < NB) bcursor[t] = t * CAP;
}

__global__ void bucket_scatter(const int* __restrict__ src, const int* __restrict__ dst,
                               int* __restrict__ bcursor, int2* __restrict__ pairs) {
    __shared__ int bins[NB];
    int wg = blockIdx.x, t = threadIdx.x;
    int e0 = wg * EPW, e1 = e0 + EPW;
    if (t < NB) bins[t] = 0;
    __syncthreads();
    for (int i = e0 + t; i < e1; i += 256)
        atomicAdd(&bins[dst[i] / BW], 1);
    __syncthreads();
    if (t < NB) {
        int c = bins[t];
        bins[t] = c ? atomicAdd(&bcursor[t], c) : 0;
    }
    __syncthreads();
    for (int i = e0 + t; i < e1; i += 256) {
        int s = src[i], d = dst[i];
        int pos = atomicAdd(&bins[d / BW], 1);
        pairs[pos] = make_int2(s, d);
    }
}

__global__ void bucket_hist(const int2* __restrict__ pairs, const int* __restrict__ bcursor,
                            int* __restrict__ cnt, float* __restrict__ dis) {
    __shared__ int h[BW];
    int b = blockIdx.x, t = threadIdx.x;
    for (int i = t; i < BW; i += 256) h[i] = 0;
    __syncthreads();
    int base = b * CAP, n = bcursor[b] - base;
    int nb = b * BW;
    for (int i = t; i < n; i += 256)
        atomicAdd(&h[pairs[base + i].y - nb], 1);
    __syncthreads();
    for (int i = t; i < BW; i += 256) {
        int c = h[i];
        cnt[nb + i] = c;
        dis[nb + i] = rsqrtf((float)c + 1.0f);
    }
}

__global__ void scan1_kernel(const int* __restrict__ cnt, int* __restrict__ sums) {
    __shared__ int lds[256];
    int b = blockIdx.x, t = threadIdx.x;
    int base = b * BW;
    int s = 0;
    if (t < BW / 4) {
#pragma unroll
        for (int k = 0; k < 4; ++k) s += cnt[base + t * 4 + k];
    }
    lds[t] = s;
    __syncthreads();
    for (int off = 128; off > 0; off >>= 1) {
        if (t < off) lds[t] += lds[t + off];
        __syncthreads();
    }
    if (t == 0) sums[b] = lds[0];
}

__global__ void scan2_kernel(const int* __restrict__ sums, int* __restrict__ offs,
                             int* __restrict__ row_start) {
    __shared__ int lds[256];
    int t = threadIdx.x;
    int own = (t < NB) ? sums[t] : 0;
    lds[t] = own;
    __syncthreads();
    for (int off = 1; off < 256; off <<= 1) {
        int v = (t >= off) ? lds[t - off] : 0;
        __syncthreads();
        lds[t] += v;
        __syncthreads();
    }
    if (t < NB) offs[t] = lds[t] - own;
    if (t == 0) row_start[N_NODES] = N_EDGES;
}

__global__ void scan3_kernel(const int* __restrict__ cnt, const int* __restrict__ offs,
                             int* __restrict__ row_start) {
    __shared__ int lds[256];
    int b = blockIdx.x, t = threadIdx.x;
    int base = b * BW;
    int local[4];
    int s = 0;
    if (t < BW / 4) {
#pragma unroll
        for (int k = 0; k < 4; ++k) { local[k] = cnt[base + t * 4 + k]; s += local[k]; }
    }
    lds[t] = s;
    __syncthreads();
    for (int off = 1; off < 256; off <<= 1) {
        int v = (t >= off) ? lds[t - off] : 0;
        __syncthreads();
        lds[t] += v;
        __syncthreads();
    }
    if (t < BW / 4) {
        int pre = lds[t] - s + offs[b];
#pragma unroll
        for (int k = 0; k < 4; ++k) {
            row_start[base + t * 4 + k] = pre;
            pre += local[k];
        }
    }
}

__global__ void bucket_fill(const int2* __restrict__ pairs, const int* __restrict__ bcursor,
                            const int* __restrict__ row_start, int* __restrict__ csr) {
    __shared__ int cur[BW];
    int b = blockIdx.x, t = threadIdx.x;  // 512 threads
    int nb = b * BW;
    for (int i = t; i < BW; i += 512) cur[i] = row_start[nb + i];
    __syncthreads();
    int base = b * CAP, n = bcursor[b] - base;
    for (int i = t; i < n; i += 512) {
        int2 p = pairs[base + i];
        int pos = atomicAdd(&cur[p.y - nb], 1);
        csr[pos] = p.x;
    }
}

// ---------- compute ----------

// x (fp32) -> xb (bf16), 4 elems/thread
__global__ void cast_kernel(const float* __restrict__ x, unsigned short* __restrict__ xb) {
    int i = blockIdx.x * blockDim.x + threadIdx.x;
    if (i < N_NODES * D / 4) {
        float4 v = ((const float4*)x)[i];
        union { unsigned short s[4]; uint2 u; } p;
        p.s[0] = f2bf(v.x); p.s[1] = f2bf(v.y); p.s[2] = f2bf(v.z); p.s[3] = f2bf(v.w);
        ((uint2*)xb)[i] = p.u;
    }
}

// MFMA GEMM: Y[100000x64] = X[100000x64] @ W[64x64], bf16 in/out, fp32 accumulate.
// One wave per 16-row tile; B-frags (W) built once per wave, held in registers.
__global__ void mfma_gemm(const unsigned short* __restrict__ Xb, const float* __restrict__ W,
                          unsigned short* __restrict__ Y) {
    int lane = threadIdx.x & 63;
    int wid  = (blockIdx.x * blockDim.x + threadIdx.x) >> 6;
    int nwav = (gridDim.x * blockDim.x) >> 6;
    int nl = lane & 15;         // col within tile / row within A-tile
    int kq = lane >> 4;         // quad
    int kb = kq * 8;            // k base within K-step
    // B-frags: b0[nt] covers k=0..31, b1[nt] k=32..63, cols nt*16+nl
    union BV { unsigned short s[8]; bf16x8 v; } b0[4], b1[4];
#pragma unroll
    for (int nt = 0; nt < 4; ++nt) {
        int n = nt * 16 + nl;
#pragma unroll
        for (int j = 0; j < 8; ++j) {
            b0[nt].s[j] = f2bf(W[(kb + j) * 64 + n]);
            b1[nt].s[j] = f2bf(W[(32 + kb + j) * 64 + n]);
        }
    }
    const uint4* X4 = (const uint4*)Xb;   // 8 uint4 per 64-elem row
    for (int t = wid; t < N_NODES / 16; t += nwav) {
        int m0 = t * 16;
        uint4 a0u = X4[(size_t)(m0 + nl) * 8 + kq];        // k = kb..kb+7
        uint4 a1u = X4[(size_t)(m0 + nl) * 8 + 4 + kq];    // k = 32+kb..
        bf16x8 a0 = __builtin_bit_cast(bf16x8, a0u);
        bf16x8 a1 = __builtin_bit_cast(bf16x8, a1u);
        f32x4 acc[4];
#pragma unroll
        for (int nt = 0; nt < 4; ++nt) {
            acc[nt] = (f32x4){0.0f, 0.0f, 0.0f, 0.0f};
            acc[nt] = __builtin_amdgcn_mfma_f32_16x16x32_bf16(a0, b0[nt].v, acc[nt], 0, 0, 0);
            acc[nt] = __builtin_amdgcn_mfma_f32_16x16x32_bf16(a1, b1[nt].v, acc[nt], 0, 0, 0);
        }
        int rbase = m0 + kq * 4;   // D: row = quad*4 + reg, col = nl
#pragma unroll
        for (int nt = 0; nt < 4; ++nt) {
            int n = nt * 16 + nl;
#pragma unroll
            for (int r = 0; r < 4; ++r)
                Y[(size_t)(rbase + r) * 64 + n] = f2bf(acc[nt][r]);
        }
    }
}

// one wave per dst node; 8 lanes per edge, each lane loads uint4 = 8 bf16 feats.
// out_bf16: write packed bf16 row (feeds next MFMA GEMM); else fp32.
__global__ void gather_kernel(const unsigned short* __restrict__ Hb, const int* __restrict__ csr,
                              const int* __restrict__ row_start, const float* __restrict__ dis,
                              const float* __restrict__ bias, void* __restrict__ Out,
                              int do_relu, int out_bf16) {
    int v    = (blockIdx.x * blockDim.x + threadIdx.x) >> 6;
    int lane = threadIdx.x & 63;
    int oct  = lane >> 3;                 // 0..7: edge slot within iteration
    int l8   = lane & 7;                  // feature octet: feats 8*l8 .. 8*l8+7
    if (v >= N_NODES) return;
    int base = row_start[v];
    int n = row_start[v + 1] - base;
    float disv = dis[v];
    const uint4* H4 = (const uint4*)Hb;   // row = 8 x uint4 (64 bf16)

    float a0 = 0, a1 = 0, a2 = 0, a3 = 0, a4 = 0, a5 = 0, a6 = 0, a7 = 0;
    if (oct == 0) {
        uint4 hv = H4[(size_t)v * 8 + l8];
        float ss = disv * disv;
        float4 blo = ((const float4*)bias)[2 * l8];
        float4 bhi = ((const float4*)bias)[2 * l8 + 1];
        a0 = fmaf(bf_lo(hv.x), ss, blo.x); a1 = fmaf(bf_hi(hv.x), ss, blo.y);
        a2 = fmaf(bf_lo(hv.y), ss, blo.z); a3 = fmaf(bf_hi(hv.y), ss, blo.w);
        a4 = fmaf(bf_lo(hv.z), ss, bhi.x); a5 = fmaf(bf_hi(hv.z), ss, bhi.y);
        a6 = fmaf(bf_lo(hv.w), ss, bhi.z); a7 = fmaf(bf_hi(hv.w), ss, bhi.w);
    }

    for (int c = 0; c < n; c += 64) {
        int m = min(64, n - c);
        int sl = 0; float dl = 0.0f;
        if (lane < m) { sl = csr[base + c + lane]; dl = dis[sl]; }
        int mp = (m + 7) >> 3;
#pragma unroll 4
        for (int t = 0; t < mp; ++t) {
            int eidx = 8 * t + oct;                // lanes >= m preloaded {0, 0.0} -> contribute 0
            int ssrc  = __shfl(sl, eidx);
            float nrm = __shfl(dl, eidx) * disv;
            uint4 hv = H4[(size_t)ssrc * 8 + l8];
            a0 = fmaf(bf_lo(hv.x), nrm, a0); a1 = fmaf(bf_hi(hv.x), nrm, a1);
            a2 = fmaf(bf_lo(hv.y), nrm, a2); a3 = fmaf(bf_hi(hv.y), nrm, a3);
            a4 = fmaf(bf_lo(hv.z), nrm, a4); a5 = fmaf(bf_hi(hv.z), nrm, a5);
            a6 = fmaf(bf_lo(hv.w), nrm, a6); a7 = fmaf(bf_hi(hv.w), nrm, a7);
        }
    }
#pragma unroll
    for (int off = 8; off <= 32; off <<= 1) {
        a0 += __shfl_xor(a0, off); a1 += __shfl_xor(a1, off);
        a2 += __shfl_xor(a2, off); a3 += __shfl_xor(a3, off);
        a4 += __shfl_xor(a4, off); a5 += __shfl_xor(a5, off);
        a6 += __shfl_xor(a6, off); a7 += __shfl_xor(a7, off);
    }
    if (oct == 0) {
        if (do_relu) {
            a0 = fmaxf(a0, 0.0f); a1 = fmaxf(a1, 0.0f); a2 = fmaxf(a2, 0.0f); a3 = fmaxf(a3, 0.0f);
            a4 = fmaxf(a4, 0.0f); a5 = fmaxf(a5, 0.0f); a6 = fmaxf(a6, 0.0f); a7 = fmaxf(a7, 0.0f);
        }
        if (out_bf16) {
            union { unsigned short s[8]; uint4 u; } p;
            p.s[0] = f2bf(a0); p.s[1] = f2bf(a1); p.s[2] = f2bf(a2); p.s[3] = f2bf(a3);
            p.s[4] = f2bf(a4); p.s[5] = f2bf(a5); p.s[6] = f2bf(a6); p.s[7] = f2bf(a7);
            ((uint4*)Out)[(size_t)v * 8 + l8] = p.u;
        } else {
            float4* o = (float4*)Out + (size_t)v * 16 + 2 * l8;
            o[0] = make_float4(a0, a1, a2, a3);
            o[1] = make_float4(a4, a5, a6, a7);
        }
    }
}

// Y[r][c] = sum_k X[r][k] * W[k][c] (+ bias) — fp32, used only for the tiny head GEMM.
__global__ void gemm_kernel(const float* __restrict__ X, const float* __restrict__ W,
                            const float* __restrict__ bias, float* __restrict__ Y,
                            int nrows) {
    __shared__ float Ws[64][64];
    for (int i = threadIdx.x; i < 64 * 64; i += 256)
        Ws[i >> 6][i & 63] = W[i];
    __syncthreads();
    int c  = threadIdx.x & 63;
    int rl = threadIdx.x >> 6;
    int r  = blockIdx.x * 4 + rl;
    if (r < nrows) {
        const float* xr = X + (size_t)r * D;
        float acc = bias ? bias[c] : 0.0f;
#pragma unroll
        for (int k = 0; k < 64; ++k)
            acc = fmaf(xr[k], Ws[k][c], acc);
        Y[(size_t)r * D + c] = acc;
    }
}

// one block per graph: mean over contiguous node segment [ptr[g], ptr[g+1])
__global__ void pool_kernel(const float* __restrict__ H, const int* __restrict__ ptr,
                            float* __restrict__ out) {
    int g = blockIdx.x;
    int start = ptr[g], end = ptr[g + 1];
    int lane  = threadIdx.x & 63;
    int chunk = threadIdx.x >> 6;
    float acc = 0.0f;
    for (int r = start + chunk; r < end; r += 4)
        acc += H[(size_t)r * D + lane];
    __shared__ float tmp[4][64];
    tmp[chunk][lane] = acc;
    __syncthreads();
    if (threadIdx.x < 64) {
        float s = tmp[0][lane] + tmp[1][lane] + tmp[2][lane] + tmp[3][lane];
        out[g * D + lane] = s / (float)(end - start);
    }
}

extern "C" void kernel_launch(void* const* d_in, const int* in_sizes, int n_in,
                              void* d_out, int out_size, void* d_ws, size_t ws_size,
                              hipStream_t stream) {
    const float* x   = (const float*)d_in[0];
    const int*   ei  = (const int*)d_in[1];
    const int*   src = ei;
    const int*   dst = ei + N_EDGES;
    const int*   ptr = (const int*)d_in[2];
    const float* W1  = (const float*)d_in[3];
    const float* b1  = (const float*)d_in[4];
    const float* W2  = (const float*)d_in[5];
    const float* b2  = (const float*)d_in[6];
    const float* Wf  = (const float*)d_in[7];
    const float* bfp = (const float*)d_in[8];
    float* out = (float*)d_out;

    // workspace layout (4-byte units)
    int*   cnt       = (int*)d_ws;                  // 100352
    int*   row_start = cnt + 100352;                // 100352 (N+1 used)
    int*   sums      = row_start + 100352;          // 256
    int*   offs      = sums + 256;                  // 256
    int*   bcursor   = offs + 256;                  // 256
    float* P         = (float*)(bcursor + 256);     // 8192 (125*64 used)
    float* dis       = P + 8192;                    // 100352
    int*   csr       = (int*)(dis + 100352);        // 3200000
    float* R         = (float*)(csr + 3200000);     // region start
    unsigned short* Ab = (unsigned short*)R;                 // bf16 N*64 (1.6M floats)
    unsigned short* Hb = (unsigned short*)(R + 1600000);     // bf16 N*64
    float* Bf        = R + 3200000;                          // fp32 N*64 (6.4M floats)
    unsigned short* xb = (unsigned short*)(R + 9600000);     // bf16 N*64
    int2*  pairs     = (int2*)R;     // NB*CAP int2 = 8.192M floats, aliases Ab..Bf (dead before gemm1)

    // --- cast x to bf16 (disjoint from pairs region) ---
    cast_kernel<<<(N_NODES * D / 4 + 255) / 256, 256, 0, stream>>>(x, xb);

    // --- CSR build ---
    init_bcursor<<<1, 256, 0, stream>>>(bcursor);
    bucket_scatter<<<NB, 256, 0, stream>>>(src, dst, bcursor, pairs);
    bucket_hist<<<NB, 256, 0, stream>>>(pairs, bcursor, cnt, dis);
    scan1_kernel<<<NB, 256, 0, stream>>>(cnt, sums);
    scan2_kernel<<<1, 256, 0, stream>>>(sums, offs, row_start);
    scan3_kernel<<<NB, 256, 0, stream>>>(cnt, offs, row_start);
    bucket_fill<<<NB, 512, 0, stream>>>(pairs, bcursor, row_start, csr);

    const int grid4 = (N_NODES + 3) / 4;

    // layer 1: Ab = bf16(xb @ W1) ; Hb = bf16(relu(gather(Ab) + Ab*dis^2 + b1))
    mfma_gemm<<<782, 256, 0, stream>>>(xb, W1, Ab);
    gather_kernel<<<grid4, 256, 0, stream>>>(Ab, csr, row_start, dis, b1, Hb, 1, 1);

    // layer 2: Ab = bf16(Hb @ W2) ; Bf = fp32(relu(gather(Ab) + Ab*dis^2 + b2))
    mfma_gemm<<<782, 256, 0, stream>>>(Hb, W2, Ab);
    gather_kernel<<<grid4, 256, 0, stream>>>(Ab, csr, row_start, dis, b2, Bf, 1, 0);

    // head: pool first (mean commutes with linear head), then tiny fp32 GEMM
    pool_kernel<<<N_GRAPHS, 256, 0, stream>>>(Bf, ptr, P);
    gemm_kernel<<<(N_GRAPHS + 3) / 4, 256, 0, stream>>>(P, Wf, bfp, out, N_GRAPHS);
}

// Round 11
// 377.014 us; speedup vs baseline: 1.7543x; 1.0463x over previous
//
#include <hip/hip_runtime.h>
#include <hip/hip_bf16.h>

#define N_NODES 100000
#define N_EDGES 3200000
#define N_GRAPHS 125
#define D 64
#define NB 800          // buckets
#define BW 125          // nodes per bucket (NB*BW == N_NODES)
#define CAP 4608        // max edges per bucket (mean 4000, sigma ~63; mean+9.6σ)
#define SC_WGS 400      // bucket_scatter workgroups
#define SC_EPW 8000     // edges per scatter wg (400*8000 == N_EDGES)

typedef __bf16 bf16x8 __attribute__((ext_vector_type(8)));
typedef float f32x4 __attribute__((ext_vector_type(4)));

__device__ __forceinline__ float bf_lo(unsigned u) { return __uint_as_float(u << 16); }
__device__ __forceinline__ float bf_hi(unsigned u) { return __uint_as_float(u & 0xffff0000u); }
// RNE float->bf16 bits (matches __float2bfloat16 for normal inputs)
__device__ __forceinline__ unsigned short f2bf(float f) {
    unsigned u = __float_as_uint(f);
    return (unsigned short)((u + 0x7fffu + ((u >> 16) & 1u)) >> 16);
}

// ---------- CSR build (bucketed, LDS-atomic) ----------

// partition edges into NB dst-range buckets; bcursor is RELATIVE (pre-zeroed)
__global__ void bucket_scatter(const int* __restrict__ src, const int* __restrict__ dst,
                               int* __restrict__ bcursor, int2* __restrict__ pairs) {
    __shared__ int bins[NB];
    int wg = blockIdx.x, t = threadIdx.x;
    int e0 = wg * SC_EPW, e1 = e0 + SC_EPW;
    for (int i = t; i < NB; i += 256) bins[i] = 0;
    __syncthreads();
    for (int i = e0 + t; i < e1; i += 256)
        atomicAdd(&bins[dst[i] / BW], 1);
    __syncthreads();
    for (int i = t; i < NB; i += 256) {
        int c = bins[i];
        bins[i] = i * CAP + (c ? atomicAdd(&bcursor[i], c) : 0);
    }
    __syncthreads();
    for (int i = e0 + t; i < e1; i += 256) {
        int s = src[i], d = dst[i];
        int pos = atomicAdd(&bins[d / BW], 1);
        pairs[pos] = make_int2(s, d);
    }
}

// per-bucket node histogram -> cnt, dis; also bucket sum -> sums[b] (folds scan1)
__global__ void bucket_hist(const int2* __restrict__ pairs, const int* __restrict__ bcursor,
                            int* __restrict__ cnt, float* __restrict__ dis,
                            int* __restrict__ sums) {
    __shared__ int h[BW];
    int b = blockIdx.x, t = threadIdx.x;
    for (int i = t; i < BW; i += 256) h[i] = 0;
    __syncthreads();
    int base = b * CAP, n = bcursor[b];
    int nb = b * BW;
    for (int i = t; i < n; i += 256)
        atomicAdd(&h[pairs[base + i].y - nb], 1);
    __syncthreads();
    for (int i = t; i < BW; i += 256) {
        int c = h[i];
        cnt[nb + i] = c;
        dis[nb + i] = rsqrtf((float)c + 1.0f);
    }
    __syncthreads();
    if (t < 64) {
        int s = h[t] + ((t + 64 < BW) ? h[t + 64] : 0);
#pragma unroll
        for (int off = 32; off > 0; off >>= 1) s += __shfl_down(s, off);
        if (t == 0) sums[b] = s;
    }
}

// exclusive scan of NB bucket sums -> offs; seal row_start[N]
__global__ void scan2_kernel(const int* __restrict__ sums, int* __restrict__ offs,
                             int* __restrict__ row_start) {
    __shared__ int lds[1024];
    int t = threadIdx.x;  // 1024 threads
    int own = (t < NB) ? sums[t] : 0;
    lds[t] = own;
    __syncthreads();
    for (int off = 1; off < 1024; off <<= 1) {
        int v = (t >= off) ? lds[t - off] : 0;
        __syncthreads();
        lds[t] += v;
        __syncthreads();
    }
    if (t < NB) offs[t] = lds[t] - own;
    if (t == 0) row_start[N_NODES] = N_EDGES;
}

// per-bucket: in-LDS exclusive scan of cnt (folds scan3) -> row_start + cursors,
// then CSR fill with LDS cursors
__global__ void bucket_fill(const int2* __restrict__ pairs, const int* __restrict__ bcursor,
                            const int* __restrict__ cnt, const int* __restrict__ offs,
                            int* __restrict__ row_start, int* __restrict__ csr) {
    __shared__ int sc[128];
    __shared__ int cur[BW];
    int b = blockIdx.x, t = threadIdx.x;  // 512 threads
    int nb = b * BW;
    int own = 0;
    if (t < 128) {
        own = (t < BW) ? cnt[nb + t] : 0;
        sc[t] = own;
    }
    __syncthreads();
    for (int off = 1; off < 128; off <<= 1) {
        int v = (t >= off && t < 128) ? sc[t - off] : 0;
        __syncthreads();
        if (t < 128) sc[t] += v;
        __syncthreads();
    }
    if (t < BW) {
        int rs = offs[b] + sc[t] - own;   // exclusive prefix + bucket offset
        row_start[nb + t] = rs;
        cur[t] = rs;
    }
    __syncthreads();
    int base = b * CAP, n = bcursor[b];
    for (int i = t; i < n; i += 512) {
        int2 p = pairs[base + i];
        int pos = atomicAdd(&cur[p.y - nb], 1);
        csr[pos] = p.x;
    }
}

// ---------- compute ----------

// x (fp32) -> xb (bf16), 4 elems/thread
__global__ void cast_kernel(const float* __restrict__ x, unsigned short* __restrict__ xb) {
    int i = blockIdx.x * blockDim.x + threadIdx.x;
    if (i < N_NODES * D / 4) {
        float4 v = ((const float4*)x)[i];
        union { unsigned short s[4]; uint2 u; } p;
        p.s[0] = f2bf(v.x); p.s[1] = f2bf(v.y); p.s[2] = f2bf(v.z); p.s[3] = f2bf(v.w);
        ((uint2*)xb)[i] = p.u;
    }
}

// MFMA GEMM: Y[100000x64] = X[100000x64] @ W[64x64], bf16 in/out, fp32 accumulate.
__global__ void mfma_gemm(const unsigned short* __restrict__ Xb, const float* __restrict__ W,
                          unsigned short* __restrict__ Y) {
    int lane = threadIdx.x & 63;
    int wid  = (blockIdx.x * blockDim.x + threadIdx.x) >> 6;
    int nwav = (gridDim.x * blockDim.x) >> 6;
    int nl = lane & 15;         // col within tile / row within A-tile
    int kq = lane >> 4;         // quad
    int kb = kq * 8;            // k base within K-step
    union BV { unsigned short s[8]; bf16x8 v; } b0[4], b1[4];
#pragma unroll
    for (int nt = 0; nt < 4; ++nt) {
        int n = nt * 16 + nl;
#pragma unroll
        for (int j = 0; j < 8; ++j) {
            b0[nt].s[j] = f2bf(W[(kb + j) * 64 + n]);
            b1[nt].s[j] = f2bf(W[(32 + kb + j) * 64 + n]);
        }
    }
    const uint4* X4 = (const uint4*)Xb;   // 8 uint4 per 64-elem row
    for (int t = wid; t < N_NODES / 16; t += nwav) {
        int m0 = t * 16;
        uint4 a0u = X4[(size_t)(m0 + nl) * 8 + kq];
        uint4 a1u = X4[(size_t)(m0 + nl) * 8 + 4 + kq];
        bf16x8 a0 = __builtin_bit_cast(bf16x8, a0u);
        bf16x8 a1 = __builtin_bit_cast(bf16x8, a1u);
        f32x4 acc[4];
#pragma unroll
        for (int nt = 0; nt < 4; ++nt) {
            acc[nt] = (f32x4){0.0f, 0.0f, 0.0f, 0.0f};
            acc[nt] = __builtin_amdgcn_mfma_f32_16x16x32_bf16(a0, b0[nt].v, acc[nt], 0, 0, 0);
            acc[nt] = __builtin_amdgcn_mfma_f32_16x16x32_bf16(a1, b1[nt].v, acc[nt], 0, 0, 0);
        }
        int rbase = m0 + kq * 4;   // D: row = quad*4 + reg, col = nl
#pragma unroll
        for (int nt = 0; nt < 4; ++nt) {
            int n = nt * 16 + nl;
#pragma unroll
            for (int r = 0; r < 4; ++r)
                Y[(size_t)(rbase + r) * 64 + n] = f2bf(acc[nt][r]);
        }
    }
}

// one wave per dst node; 8 lanes per edge, each lane loads uint4 = 8 bf16 feats.
__global__ void gather_kernel(const unsigned short* __restrict__ Hb, const int* __restrict__ csr,
                              const int* __restrict__ row_start, const float* __restrict__ dis,
                              const float* __restrict__ bias, void* __restrict__ Out,
                              int do_relu, int out_bf16) {
    int v    = (blockIdx.x * blockDim.x + threadIdx.x) >> 6;
    int lane = threadIdx.x & 63;
    int oct  = lane >> 3;
    int l8   = lane & 7;
    if (v >= N_NODES) return;
    int base = row_start[v];
    int n = row_start[v + 1] - base;
    float disv = dis[v];
    const uint4* H4 = (const uint4*)Hb;

    float a0 = 0, a1 = 0, a2 = 0, a3 = 0, a4 = 0, a5 = 0, a6 = 0, a7 = 0;
    if (oct == 0) {
        uint4 hv = H4[(size_t)v * 8 + l8];
        float ss = disv * disv;
        float4 blo = ((const float4*)bias)[2 * l8];
        float4 bhi = ((const float4*)bias)[2 * l8 + 1];
        a0 = fmaf(bf_lo(hv.x), ss, blo.x); a1 = fmaf(bf_hi(hv.x), ss, blo.y);
        a2 = fmaf(bf_lo(hv.y), ss, blo.z); a3 = fmaf(bf_hi(hv.y), ss, blo.w);
        a4 = fmaf(bf_lo(hv.z), ss, bhi.x); a5 = fmaf(bf_hi(hv.z), ss, bhi.y);
        a6 = fmaf(bf_lo(hv.w), ss, bhi.z); a7 = fmaf(bf_hi(hv.w), ss, bhi.w);
    }

    for (int c = 0; c < n; c += 64) {
        int m = min(64, n - c);
        int sl = 0; float dl = 0.0f;
        if (lane < m) { sl = csr[base + c + lane]; dl = dis[sl]; }
        int mp = (m + 7) >> 3;
#pragma unroll 4
        for (int t = 0; t < mp; ++t) {
            int eidx = 8 * t + oct;
            int ssrc  = __shfl(sl, eidx);
            float nrm = __shfl(dl, eidx) * disv;
            uint4 hv = H4[(size_t)ssrc * 8 + l8];
            a0 = fmaf(bf_lo(hv.x), nrm, a0); a1 = fmaf(bf_hi(hv.x), nrm, a1);
            a2 = fmaf(bf_lo(hv.y), nrm, a2); a3 = fmaf(bf_hi(hv.y), nrm, a3);
            a4 = fmaf(bf_lo(hv.z), nrm, a4); a5 = fmaf(bf_hi(hv.z), nrm, a5);
            a6 = fmaf(bf_lo(hv.w), nrm, a6); a7 = fmaf(bf_hi(hv.w), nrm, a7);
        }
    }
#pragma unroll
    for (int off = 8; off <= 32; off <<= 1) {
        a0 += __shfl_xor(a0, off); a1 += __shfl_xor(a1, off);
        a2 += __shfl_xor(a2, off); a3 += __shfl_xor(a3, off);
        a4 += __shfl_xor(a4, off); a5 += __shfl_xor(a5, off);
        a6 += __shfl_xor(a6, off); a7 += __shfl_xor(a7, off);
    }
    if (oct == 0) {
        if (do_relu) {
            a0 = fmaxf(a0, 0.0f); a1 = fmaxf(a1, 0.0f); a2 = fmaxf(a2, 0.0f); a3 = fmaxf(a3, 0.0f);
            a4 = fmaxf(a4, 0.0f); a5 = fmaxf(a5, 0.0f); a6 = fmaxf(a6, 0.0f); a7 = fmaxf(a7, 0.0f);
        }
        if (out_bf16) {
            union { unsigned short s[8]; uint4 u; } p;
            p.s[0] = f2bf(a0); p.s[1] = f2bf(a1); p.s[2] = f2bf(a2); p.s[3] = f2bf(a3);
            p.s[4] = f2bf(a4); p.s[5] = f2bf(a5); p.s[6] = f2bf(a6); p.s[7] = f2bf(a7);
            ((uint4*)Out)[(size_t)v * 8 + l8] = p.u;
        } else {
            float4* o = (float4*)Out + (size_t)v * 16 + 2 * l8;
            o[0] = make_float4(a0, a1, a2, a3);
            o[1] = make_float4(a4, a5, a6, a7);
        }
    }
}

// Y[r][c] = sum_k X[r][k] * W[k][c] (+ bias) — fp32, tiny head GEMM only.
__global__ void gemm_kernel(const float* __restrict__ X, const float* __restrict__ W,
                            const float* __restrict__ bias, float* __restrict__ Y,
                            int nrows) {
    __shared__ float Ws[64][64];
    for (int i = threadIdx.x; i < 64 * 64; i += 256)
        Ws[i >> 6][i & 63] = W[i];
    __syncthreads();
    int c  = threadIdx.x & 63;
    int rl = threadIdx.x >> 6;
    int r  = blockIdx.x * 4 + rl;
    if (r < nrows) {
        const float* xr = X + (size_t)r * D;
        float acc = bias ? bias[c] : 0.0f;
#pragma unroll
        for (int k = 0; k < 64; ++k)
            acc = fmaf(xr[k], Ws[k][c], acc);
        Y[(size_t)r * D + c] = acc;
    }
}

// one block per graph: mean over contiguous node segment [ptr[g], ptr[g+1])
__global__ void pool_kernel(const float* __restrict__ H, const int* __restrict__ ptr,
                            float* __restrict__ out) {
    int g = blockIdx.x;
    int start = ptr[g], end = ptr[g + 1];
    int lane  = threadIdx.x & 63;
    int chunk = threadIdx.x >> 6;
    float acc = 0.0f;
    for (int r = start + chunk; r < end; r += 4)
        acc += H[(size_t)r * D + lane];
    __shared__ float tmp[4][64];
    tmp[chunk][lane] = acc;
    __syncthreads();
    if (threadIdx.x < 64) {
        float s = tmp[0][lane] + tmp[1][lane] + tmp[2][lane] + tmp[3][lane];
        out[g * D + lane] = s / (float)(end - start);
    }
}

extern "C" void kernel_launch(void* const* d_in, const int* in_sizes, int n_in,
                              void* d_out, int out_size, void* d_ws, size_t ws_size,
                              hipStream_t stream) {
    const float* x   = (const float*)d_in[0];
    const int*   ei  = (const int*)d_in[1];
    const int*   src = ei;
    const int*   dst = ei + N_EDGES;
    const int*   ptr = (const int*)d_in[2];
    const float* W1  = (const float*)d_in[3];
    const float* b1  = (const float*)d_in[4];
    const float* W2  = (const float*)d_in[5];
    const float* b2  = (const float*)d_in[6];
    const float* Wf  = (const float*)d_in[7];
    const float* bfp = (const float*)d_in[8];
    float* out = (float*)d_out;

    // workspace layout (4-byte units)
    int*   cnt       = (int*)d_ws;                  // 100352
    int*   row_start = cnt + 100352;                // 100352 (N+1 used)
    int*   sums      = row_start + 100352;          // 1024
    int*   offs      = sums + 1024;                 // 1024
    int*   bcursor   = offs + 1024;                 // 1024
    float* P         = (float*)(bcursor + 1024);    // 8192 (125*64 used)
    float* dis       = P + 8192;                    // 100352
    int*   csr       = (int*)(dis + 100352);        // 3200000
    float* R         = (float*)(csr + 3200000);     // region start
    unsigned short* Ab = (unsigned short*)R;                 // bf16 N*64 (1.6M floats)
    unsigned short* Hb = (unsigned short*)(R + 1600000);     // bf16 N*64
    float* Bf        = R + 3200000;                          // fp32 N*64 (6.4M floats)
    unsigned short* xb = (unsigned short*)(R + 9600000);     // bf16 N*64
    int2*  pairs     = (int2*)R;     // NB*CAP int2 = 29.5 MB, aliases Ab..Bf (dead before gemm1)

    // --- cast x to bf16 (disjoint from pairs region) ---
    cast_kernel<<<(N_NODES * D / 4 + 255) / 256, 256, 0, stream>>>(x, xb);

    // --- CSR build ---
    hipMemsetAsync(bcursor, 0, NB * sizeof(int), stream);
    bucket_scatter<<<SC_WGS, 256, 0, stream>>>(src, dst, bcursor, pairs);
    bucket_hist<<<NB, 256, 0, stream>>>(pairs, bcursor, cnt, dis, sums);
    scan2_kernel<<<1, 1024, 0, stream>>>(sums, offs, row_start);
    bucket_fill<<<NB, 512, 0, stream>>>(pairs, bcursor, cnt, offs, row_start, csr);

    const int grid4 = (N_NODES + 3) / 4;

    // layer 1: Ab = bf16(xb @ W1) ; Hb = bf16(relu(gather(Ab) + Ab*dis^2 + b1))
    mfma_gemm<<<782, 256, 0, stream>>>(xb, W1, Ab);
    gather_kernel<<<grid4, 256, 0, stream>>>(Ab, csr, row_start, dis, b1, Hb, 1, 1);

    // layer 2: Ab = bf16(Hb @ W2) ; Bf = fp32(relu(gather(Ab) + Ab*dis^2 + b2))
    mfma_gemm<<<782, 256, 0, stream>>>(Hb, W2, Ab);
    gather_kernel<<<grid4, 256, 0, stream>>>(Ab, csr, row_start, dis, b2, Bf, 1, 0);

    // head: pool first (mean commutes with linear head), then tiny fp32 GEMM
    pool_kernel<<<N_GRAPHS, 256, 0, stream>>>(Bf, ptr, P);
    gemm_kernel<<<(N_GRAPHS + 3) / 4, 256, 0, stream>>>(P, Wf, bfp, out, N_GRAPHS);
}